// Round 4
// baseline (108.236 us; speedup 1.0000x reference)
//
#include <hip/hip_runtime.h>
#include <cstdint>

typedef unsigned long long u64;
typedef unsigned int u32;

#define DIM     10000
#define NCLS    100
#define BATCH   4096
#define WORDS32 320      // u32 words per packed row (10240 bits; 240 pad bits = 0)
#define WORDS64 160      // same row viewed as u64
#define NC      10       // classes per hamming block

// Bit layout (LINEAR, identical for q and am): dim d -> u32 word d>>5, bit d&31.
// Word w = it*64 + lane covers dims [it*2048 + lane*32, +32). Pad dims are 0
// on BOTH operands -> XOR contributes nothing.

// one wave per row; each iteration: wave reads 8 KB contiguous, writes 256 B.
__device__ __forceinline__ void pack_row(const float* __restrict__ row,
                                         u32* __restrict__ orow, const int lane) {
    for (int it = 0; it < 5; ++it) {
        const int base = it * 2048 + lane * 32;     // this lane's 32 floats
        u32 piece = 0;
        if (base + 32 <= DIM) {                     // fast path (all but tail lanes)
#pragma unroll
            for (int k8 = 0; k8 < 8; ++k8) {
                const float4 v = *(const float4*)(row + base + k8 * 4);
                piece |= (v.x > 0.5f ? 1u : 0u) << (k8 * 4 + 0);
                piece |= (v.y > 0.5f ? 1u : 0u) << (k8 * 4 + 1);
                piece |= (v.z > 0.5f ? 1u : 0u) << (k8 * 4 + 2);
                piece |= (v.w > 0.5f ? 1u : 0u) << (k8 * 4 + 3);
            }
        } else {                                    // it==4, lanes 56..63 only
            for (int k = 0; k < 32; ++k) {
                const int d = base + k;
                const float v = (d < DIM) ? row[d] : 0.0f;
                piece |= (v > 0.5f ? 1u : 0u) << k;
            }
        }
        orow[it * 64 + lane] = piece;               // full-wave 256 B contiguous
    }
}

// grid: nrows/4 blocks x 256 threads (4 waves, one row each)
__global__ __launch_bounds__(256) void pack_kernel(const float* __restrict__ in,
                                                   u32* __restrict__ out32,
                                                   const int nrows) {
    const int lane = threadIdx.x & 63;
    const int r    = blockIdx.x * 4 + (threadIdx.x >> 6);
    if (r >= nrows) return;
    pack_row(in + (size_t)r * DIM, out32 + (size_t)r * WORDS32, lane);
}

// lane = one query row (streams its own contiguous packed row; L2-resident).
// ap indices are wave-uniform -> scalar loads. grid (16, NCLS/NC, 2), block 256.
__global__ __launch_bounds__(256) void hamming_kernel(const u64* __restrict__ qp,
                                                      const u64* __restrict__ ap,
                                                      float* __restrict__ out) {
    const int r  = blockIdx.x * 256 + threadIdx.x;
    const int c0 = blockIdx.y * NC;
    const int w0 = blockIdx.z * (WORDS64 / 2);      // 80 u64 words per z-half
    const u64* qrow  = qp + (size_t)r * WORDS64 + w0;
    const u64* abase = ap + w0;
    int acc[NC];
#pragma unroll
    for (int j = 0; j < NC; ++j) acc[j] = 0;

#pragma unroll 2
    for (int w = 0; w < WORDS64 / 2; w += 2) {
        const ulonglong2 qv = *(const ulonglong2*)(qrow + w);   // 16 B/lane
#pragma unroll
        for (int j = 0; j < NC; ++j) {
            const u64 a0 = abase[(size_t)(c0 + j) * WORDS64 + w];     // uniform
            const u64 a1 = abase[(size_t)(c0 + j) * WORDS64 + w + 1]; // uniform
            acc[j] += __popcll(qv.x ^ a0) + __popcll(qv.y ^ a1);
        }
    }
    const float base = (blockIdx.z == 0) ? (float)DIM : 0.0f;
#pragma unroll
    for (int j = 0; j < NC; ++j)
        atomicAdd(&out[(size_t)r * NCLS + c0 + j], base - (float)acc[j]);
}

extern "C" void kernel_launch(void* const* d_in, const int* in_sizes, int n_in,
                              void* d_out, int out_size, void* d_ws, size_t ws_size,
                              hipStream_t stream) {
    const float* q = (const float*)d_in[0];   // [4096, 10000] f32 {0,1}
    const float* a = (const float*)d_in[1];   // [100, 10000]  f32 {0,1}
    float* out = (float*)d_out;               // [4096, 100]   f32

    // ws: ap (100*320*4 = 128 KB) at 0; qp (4096*320*4 = 5.24 MB) at 256 KiB
    u32* ap32 = (u32*)d_ws;
    u32* qp32 = (u32*)((char*)d_ws + (256u << 10));

    (void)hipMemsetAsync(d_out, 0, (size_t)BATCH * NCLS * sizeof(float), stream);
    pack_kernel<<<25,   256, 0, stream>>>(a, ap32, NCLS);
    pack_kernel<<<1024, 256, 0, stream>>>(q, qp32, BATCH);
    hamming_kernel<<<dim3(16, NCLS / NC, 2), 256, 0, stream>>>(
        (const u64*)qp32, (const u64*)ap32, out);
}

// Round 5
// 74.712 us; speedup vs baseline: 1.4487x; 1.4487x over previous
//
#include <hip/hip_runtime.h>
#include <cstdint>

typedef unsigned long long u64;
typedef unsigned int u32;
typedef unsigned char u8;

#define DIM     10000
#define NCLS    100
#define BATCH   4096
#define F4ROW   2500        // float4s per input row (10000/4)
#define ROWB    2560        // padded bytes per packed row
#define W64     320         // u64 words per packed row (2560/8)
#define NC      10          // classes per hamming block
#define ZSPLIT  4           // word-range split
#define WZ      (W64 / ZSPLIT)   // 80 u64 per z-slice
#define OUTN    (BATCH * NCLS)   // 409600

// Nibble packing: float4 #i of a row -> byte i, bits 0..3 = (v.{x,y,z,w} > 0.5).
// XOR + popcount over bytes counts bit mismatches exactly (pad bytes are 0 in
// BOTH q and am -> contribute nothing). All loads: lane i <- base + 16*i
// (canonical coalesced float4 stream); all stores: 64 consecutive bytes/wave.

// one block (4 waves) per row; wave wq covers f4 indices [wq*640, wq*640+640)
__global__ __launch_bounds__(256) void pack_kernel(const float* __restrict__ in,
                                                   u8* __restrict__ outp) {
    const int lane = threadIdx.x & 63;
    const int wq   = threadIdx.x >> 6;
    const int r    = blockIdx.x;
    const float* row = in + (size_t)r * DIM;
    u8* orow = outp + (size_t)r * ROWB;
#pragma unroll
    for (int u = 0; u < 10; ++u) {
        const int idx = wq * 640 + u * 64 + lane;       // byte / f4 index, <= 2559
        float4 v = make_float4(0.f, 0.f, 0.f, 0.f);
        if (idx < F4ROW) v = *(const float4*)(row + (size_t)idx * 4);
        const u8 b = (u8)((v.x > 0.5f ? 1u : 0u) | (v.y > 0.5f ? 2u : 0u) |
                          (v.z > 0.5f ? 4u : 0u) | (v.w > 0.5f ? 8u : 0u));
        orow[idx] = b;                                   // 64 B contiguous per wave
    }
}

// lane = one query row; each block: 256 rows x NC classes x 1/ZSPLIT of words.
// grid (BATCH/256, NCLS/NC, ZSPLIT). No atomics: disjoint partial buffers.
__global__ __launch_bounds__(256) void hamming_kernel(const u64* __restrict__ qp,
                                                      const u64* __restrict__ ap,
                                                      int* __restrict__ partial) {
    const int r  = blockIdx.x * 256 + threadIdx.x;
    const int c0 = blockIdx.y * NC;
    const int z  = blockIdx.z;
    const u64* qrow  = qp + (size_t)r * W64 + (size_t)z * WZ;
    const u64* abase = ap + (size_t)z * WZ;

    int acc[NC];
#pragma unroll
    for (int j = 0; j < NC; ++j) acc[j] = 0;

    for (int wt = 0; wt < WZ; wt += 8) {                // 10 tiles of 8 u64
        ulonglong2 qv[4];
#pragma unroll
        for (int k = 0; k < 4; ++k)
            qv[k] = *(const ulonglong2*)(qrow + wt + 2 * k);  // 16 B/lane
#pragma unroll
        for (int j = 0; j < NC; ++j) {
            const u64* aw = abase + (size_t)(c0 + j) * W64 + wt;  // wave-uniform
            int s = 0;
#pragma unroll
            for (int k = 0; k < 4; ++k) {
                s += __popcll(qv[k].x ^ aw[2 * k]);
                s += __popcll(qv[k].y ^ aw[2 * k + 1]);
            }
            acc[j] += s;
        }
    }
    int* pout = partial + (size_t)z * OUTN + (size_t)r * NCLS + c0;
#pragma unroll
    for (int j = 0; j < NC; ++j) pout[j] = acc[j];
}

// out = DIM - sum_z partial[z]  (exact small ints -> exact float)
__global__ __launch_bounds__(256) void combine_kernel(const int* __restrict__ partial,
                                                      float* __restrict__ out) {
    const int i = blockIdx.x * 256 + threadIdx.x;
    const int s = partial[i] + partial[i + OUTN] + partial[i + 2 * OUTN] +
                  partial[i + 3 * OUTN];
    out[i] = (float)(DIM - s);
}

extern "C" void kernel_launch(void* const* d_in, const int* in_sizes, int n_in,
                              void* d_out, int out_size, void* d_ws, size_t ws_size,
                              hipStream_t stream) {
    const float* q = (const float*)d_in[0];   // [4096, 10000] f32 {0,1}
    const float* a = (const float*)d_in[1];   // [100, 10000]  f32 {0,1}
    float* out = (float*)d_out;               // [4096, 100]   f32

    // ws layout (all 16B-aligned):
    //   ap:      offset 0        (100*2560  = 256,000 B)
    //   qp:      offset 512 KiB  (4096*2560 = 10,485,760 B)
    //   partial: offset 12 MiB   (4*409600*4 = 6,553,600 B)
    u8*  ap8  = (u8*)d_ws;
    u8*  qp8  = (u8*)d_ws + (512u << 10);
    int* part = (int*)((char*)d_ws + (12u << 20));

    pack_kernel<<<NCLS,  256, 0, stream>>>(a, ap8);
    pack_kernel<<<BATCH, 256, 0, stream>>>(q, qp8);
    hamming_kernel<<<dim3(BATCH / 256, NCLS / NC, ZSPLIT), 256, 0, stream>>>(
        (const u64*)qp8, (const u64*)ap8, part);
    combine_kernel<<<OUTN / 256, 256, 0, stream>>>(part, out);
}